// Round 9
// baseline (115.038 us; speedup 1.0000x reference)
//
#include <hip/hip_runtime.h>
#include <cstdint>
#include <cstddef>

typedef __attribute__((ext_vector_type(8))) short bf16x8;
typedef __attribute__((ext_vector_type(4))) float f32x4;
typedef __attribute__((ext_vector_type(16))) float f32x16;
typedef __attribute__((ext_vector_type(2))) unsigned int uint32x2;

__device__ __forceinline__ unsigned short f2bf(float f) {
  unsigned int u = __builtin_bit_cast(unsigned int, f);
  u += 0x7FFFu + ((u >> 16) & 1u);
  return (unsigned short)(u >> 16);
}
__device__ __forceinline__ float bf2f(unsigned short h) {
  unsigned int u = ((unsigned int)h) << 16;
  return __builtin_bit_cast(float, u);
}
__device__ __forceinline__ unsigned cvtpk(float a, float b) {
  unsigned r;
  asm("v_cvt_pk_bf16_f32 %0, %1, %2" : "=v"(r) : "v"(a), "v"(b));
  return r;
}

__device__ __forceinline__ void gl_lds16(const unsigned short* g, unsigned short* l) {
  __builtin_amdgcn_global_load_lds(
      (const __attribute__((address_space(1))) unsigned int*)(uintptr_t)g,
      (__attribute__((address_space(3))) unsigned int*)(unsigned int)(uintptr_t)l,
      16, 0, 0);
}

// ============ k_prep: convert(x) + wtrans(Wqkv) + wtrans(Wproj) + rope table ============
__global__ void k_prep(const float* __restrict__ x,
                       const float* __restrict__ Wqkv,
                       const float* __restrict__ Wproj,
                       unsigned short* __restrict__ xb,
                       unsigned short* __restrict__ wqt,
                       unsigned short* __restrict__ wpt,
                       float2* __restrict__ cstab) {
  __shared__ float tile[32][33];
  const int bid = blockIdx.x, tid = threadIdx.x;
  if (bid < 4096) {
    int i = bid * 256 + tid;
    float4 v = reinterpret_cast<const float4*>(x)[i];
    uint2 o;
    o.x = (unsigned int)f2bf(v.x) | ((unsigned int)f2bf(v.y) << 16);
    o.y = (unsigned int)f2bf(v.z) | ((unsigned int)f2bf(v.w) << 16);
    reinterpret_cast<uint2*>(xb)[i] = o;
  } else if (bid < 8192) {
    const float* in; unsigned short* out; int rows, cols, bx, by;
    if (bid < 7168) { in = Wqkv; out = wqt; rows = 1024; cols = 3072; bx = (bid - 4096) % 96; by = (bid - 4096) / 96; }
    else            { in = Wproj; out = wpt; rows = 1024; cols = 1024; bx = (bid - 7168) % 32; by = (bid - 7168) / 32; }
    int c0 = bx * 32, r0 = by * 32;
    int tx = tid & 31, ty = tid >> 5;
#pragma unroll
    for (int j = 0; j < 4; j++)
      tile[ty + j * 8][tx] = in[(size_t)(r0 + ty + j * 8) * cols + c0 + tx];
    __syncthreads();
#pragma unroll
    for (int j = 0; j < 4; j++)
      out[(size_t)(c0 + ty + j * 8) * rows + r0 + tx] = f2bf(tile[tx][ty + j * 8]);
  } else {
    int i = (bid - 8192) * 256 + tid;   // t*32 + j
    int t = i >> 5, j = i & 31;
    float invf = __powf(10000.0f, -(float)j / 32.0f);
    float ang = (float)t * invf;
    cstab[i] = make_float2(cosf(ang), sinf(ang));
  }
}

// ============ qkv GEMM with fused RoPE/head-split/V-transpose epilogue ============
__global__ void k_gemm_qkv(const unsigned short* __restrict__ A,
                           const unsigned short* __restrict__ Bt,
                           const float2* __restrict__ cstab,
                           unsigned short* __restrict__ qh,
                           unsigned short* __restrict__ kh,
                           unsigned short* __restrict__ vt) {
  const int K = 1024;
  __shared__ unsigned short Ta[128 * 32];
  __shared__ unsigned short Tb[128 * 32];
  const int tid = threadIdx.x;
  const int bid0 = blockIdx.y * 24 + blockIdx.x;
  const int bid = (bid0 & 7) * 96 + (bid0 >> 3);
  const int m0 = (bid / 24) * 128, n0 = (bid % 24) * 128;
  const int w = tid >> 6, l = tid & 63;
  const int lr = l & 15, lg = l >> 4;
  const int wm = (w >> 1) * 64, wn = (w & 1) * 64;
  const int ssr = w * 32 + (l >> 2);
  const int ssc = (l & 3) * 8;
  unsigned short* ta0 = &Ta[w * 1024];
  unsigned short* tb0 = &Tb[w * 1024];
  f32x4 acc[4][4] = {};
  for (int k0 = 0; k0 < K; k0 += 32) {
    __syncthreads();
    gl_lds16(&A[(size_t)(m0 + ssr) * K + k0 + ssc],       ta0);
    gl_lds16(&A[(size_t)(m0 + ssr + 16) * K + k0 + ssc],  ta0 + 512);
    gl_lds16(&Bt[(size_t)(n0 + ssr) * K + k0 + ssc],      tb0);
    gl_lds16(&Bt[(size_t)(n0 + ssr + 16) * K + k0 + ssc], tb0 + 512);
    __syncthreads();
    bf16x8 af[4], bfr[4];
#pragma unroll
    for (int i = 0; i < 4; i++)
      af[i] = *(const bf16x8*)&Ta[(wm + i * 16 + lr) * 32 + lg * 8];
#pragma unroll
    for (int j = 0; j < 4; j++)
      bfr[j] = *(const bf16x8*)&Tb[(wn + j * 16 + lr) * 32 + lg * 8];
#pragma unroll
    for (int i = 0; i < 4; i++)
#pragma unroll
      for (int j = 0; j < 4; j++)
        acc[i][j] = __builtin_amdgcn_mfma_f32_16x16x32_bf16(af[i], bfr[j], acc[i][j], 0, 0, 0);
  }
  const int part = n0 >> 10;                 // 0=q, 1=k, 2=v (block-uniform)
  const int hbase = (n0 & 1023) + wn;        // multiple of 64
  if (part < 2) {
    unsigned short* dst = part ? kh : qh;
    const float scale = part ? 1.0f : 0.180336880111120420f;
#pragma unroll
    for (int i = 0; i < 4; i++) {
#pragma unroll
      for (int r = 0; r < 4; r++) {
        int gm = m0 + wm + i * 16 + lg * 4 + r;
        int t = gm & 2047, b = gm >> 11;
        float2 cs0 = cstab[t * 32 + lr];
        float2 cs1 = cstab[t * 32 + 16 + lr];
#pragma unroll
        for (int j = 0; j < 4; j++) {
          float val = acc[i][j][r];
          float par = acc[i][j ^ 2][r];
          float2 cs = (j & 1) ? cs1 : cs0;
          float out = (j < 2) ? (val * cs.x - par * cs.y)
                              : (val * cs.x + par * cs.y);
          int h = (hbase + j * 16) >> 6;
          int d = j * 16 + lr;
          int bh = b * 16 + h;
          dst[((size_t)(bh * 2048 + t)) * 64 + d] = f2bf(out * scale);
        }
      }
    }
  } else {
#pragma unroll
    for (int i = 0; i < 4; i++) {
      int tb = m0 + wm + i * 16 + lg * 4;
      int t0 = tb & 2047, b = tb >> 11;
#pragma unroll
      for (int j = 0; j < 4; j++) {
        int h = (hbase + j * 16) >> 6;
        int d = j * 16 + lr;
        int bh = b * 16 + h;
        unsigned short pv[4];
#pragma unroll
        for (int r = 0; r < 4; r++) pv[r] = f2bf(acc[i][j][r]);
        *(uint2*)&vt[((size_t)(bh * 64 + d)) * 2048 + t0] = *(uint2*)pv;
      }
    }
  }
}

// ============ proj GEMM: out[4096][1024] f32 = att x wpt^T, 64x128 tiles ============
__global__ void k_gemm_proj(const unsigned short* __restrict__ A,
                            const unsigned short* __restrict__ Bt,
                            float* __restrict__ C) {
  const int K = 1024;
  __shared__ unsigned short Ta[64 * 32];
  __shared__ unsigned short Tb[128 * 32];
  const int tid = threadIdx.x;
  const int bid0 = blockIdx.x;
  const int bid = (bid0 & 7) * 64 + (bid0 >> 3);
  const int n0 = (bid & 7) * 128;
  const int m0 = (bid >> 3) * 64;
  const int w = tid >> 6, l = tid & 63;
  const int lr = l & 15, lg = l >> 4;
  const int wn = w * 32;
  const int sra = tid >> 2, sca = (tid & 3) * 8;
  f32x4 acc[4][2] = {};
  for (int k0 = 0; k0 < K; k0 += 32) {
    __syncthreads();
    gl_lds16(&A[(size_t)(m0 + sra) * K + k0 + sca],        &Ta[tid * 8]);
    gl_lds16(&Bt[(size_t)(n0 + sra) * K + k0 + sca],       &Tb[tid * 8]);
    gl_lds16(&Bt[(size_t)(n0 + 64 + sra) * K + k0 + sca],  &Tb[(tid + 256) * 8]);
    __syncthreads();
    bf16x8 af[4], bfr[2];
#pragma unroll
    for (int i = 0; i < 4; i++)
      af[i] = *(const bf16x8*)&Ta[(i * 16 + lr) * 32 + lg * 8];
#pragma unroll
    for (int j = 0; j < 2; j++)
      bfr[j] = *(const bf16x8*)&Tb[(wn + j * 16 + lr) * 32 + lg * 8];
#pragma unroll
    for (int i = 0; i < 4; i++)
#pragma unroll
      for (int j = 0; j < 2; j++)
        acc[i][j] = __builtin_amdgcn_mfma_f32_16x16x32_bf16(af[i], bfr[j], acc[i][j], 0, 0, 0);
  }
#pragma unroll
  for (int i = 0; i < 4; i++)
#pragma unroll
    for (int j = 0; j < 2; j++)
#pragma unroll
      for (int r = 0; r < 4; r++)
        C[(size_t)(m0 + i * 16 + lg * 4 + r) * 1024 + n0 + wn + j * 16 + lr] = acc[i][j][r];
}

// ---------------- causal flash attention: 32x32 MFMA core, in-register P (T12) --------
// Same as round 8, with the O-store transpose read FIXED: 2 lanes/row x 4 uint4 each
// (was 2 uint4 -> half the d-columns never written, absmax 3.08).
__global__ __launch_bounds__(256, 2) void k_attn(const unsigned short* __restrict__ qh,
                       const unsigned short* __restrict__ kh,
                       const unsigned short* __restrict__ vt,
                       unsigned short* __restrict__ att) {
  __shared__ char SMEM[32768];   // 2 bufs x (K 8KB + V 8KB); buf0 reused for O-store
  const int bid = blockIdx.x;
  const int xcd = bid & 7, u = bid >> 3;
  int hl, qt;
  if (u < 32) { hl = u >> 3; qt = u & 7; }
  else        { hl = (u - 32) >> 3; qt = 15 - ((u - 32) & 7); }
  const int bh = xcd * 4 + hl;
  const int b = bh >> 4, h = bh & 15;
  const int tid = threadIdx.x;
  const int w = tid >> 6, l = tid & 63;
  const int lq = l & 31, g = l >> 5;
  const unsigned short* qbase = qh + (size_t)bh * 2048 * 64;
  const unsigned short* kbase = kh + (size_t)bh * 2048 * 64;
  const unsigned short* vbase = vt + (size_t)bh * 64 * 2048;
  const int swz = (lq & 7) << 4;
  const int sr = tid >> 2, sc = (tid & 3) * 16;
  const int sb0 = (sr * 128 + sc * 2) ^ ((sr & 7) << 4);
  const int sb1 = (sr * 128 + sc * 2 + 16) ^ ((sr & 7) << 4);

  const int q0 = qt * 128;
  const int wq = q0 + 32 * w;
  const int qrow = wq + lq;
  bf16x8 qf[4];
#pragma unroll
  for (int dt = 0; dt < 4; dt++)
    qf[dt] = *(const bf16x8*)&qbase[(size_t)qrow * 64 + dt * 16 + g * 8];

  float mr = -3.0e38f, ls = 0.0f;
  f32x16 of0 = {}, of1 = {};
  uint4 ka0, ka1, va0, va1;

  auto issue = [&](int kv0) {
    const unsigned short* ksrc = &kbase[(size_t)(kv0 + sr) * 64 + sc];
    const unsigned short* vsrc = &vbase[(size_t)sr * 2048 + kv0 + sc];
    ka0 = *(const uint4*)ksrc; ka1 = *(const uint4*)(ksrc + 8);
    va0 = *(const uint4*)vsrc; va1 = *(const uint4*)(vsrc + 8);
  };

  const int nkv = 2 * qt + 2;   // always even
  issue(0);
  {
    char* KB0 = SMEM;
    char* VB0 = SMEM + 8192;
    *(uint4*)(KB0 + sb0) = ka0;  *(uint4*)(KB0 + sb1) = ka1;
    *(uint4*)(VB0 + sb0) = va0;  *(uint4*)(VB0 + sb1) = va1;
  }
  __syncthreads();

  for (int t = 0; t < nkv; t++) {
    const int kv0 = t * 64;
    char* KBc = SMEM + (t & 1) * 16384;
    char* VBc = KBc + 8192;
    if (t + 1 < nkv) issue(kv0 + 64);
    if (kv0 <= wq + 31) {
      // ---- QK^T: S^T[k][q], two k-halves ----
      f32x16 s0 = {}, s1 = {};
      __builtin_amdgcn_s_setprio(1);
#pragma unroll
      for (int dt = 0; dt < 4; dt++) {
        bf16x8 k0 = *(const bf16x8*)(KBc + lq * 128 + ((dt * 32 + g * 16) ^ swz));
        bf16x8 k1 = *(const bf16x8*)(KBc + (32 + lq) * 128 + ((dt * 32 + g * 16) ^ swz));
        s0 = __builtin_amdgcn_mfma_f32_32x32x16_bf16(k0, qf[dt], s0, 0, 0, 0);
        s1 = __builtin_amdgcn_mfma_f32_32x32x16_bf16(k1, qf[dt], s1, 0, 0, 0);
      }
      __builtin_amdgcn_s_setprio(0);
      // ---- causal mask (diagonal region only) ----
      if (kv0 + 63 > wq) {
#pragma unroll
        for (int r = 0; r < 16; r++) {
          int kk = kv0 + (r & 3) + 8 * (r >> 2) + 4 * g;
          if (kk > qrow)      s0[r] = -3.0e38f;
          if (kk + 32 > qrow) s1[r] = -3.0e38f;
        }
      }
      // ---- online softmax (base-2; scale folded into Q); T13 defer-max ----
      float pm = s0[0];
#pragma unroll
      for (int r = 1; r < 16; r++) pm = fmaxf(pm, s0[r]);
#pragma unroll
      for (int r = 0; r < 16; r++) pm = fmaxf(pm, s1[r]);
      pm = fmaxf(pm, __shfl_xor(pm, 32));
      if (__all(pm <= mr)) {
        float psum = 0.0f;
#pragma unroll
        for (int r = 0; r < 16; r++) { float p = __builtin_amdgcn_exp2f(s0[r] - mr); s0[r] = p; psum += p; }
#pragma unroll
        for (int r = 0; r < 16; r++) { float p = __builtin_amdgcn_exp2f(s1[r] - mr); s1[r] = p; psum += p; }
        psum += __shfl_xor(psum, 32);
        ls += psum;
      } else {
        float mnew = fmaxf(mr, pm);
        float alpha = __builtin_amdgcn_exp2f(mr - mnew);
        mr = mnew;
        float psum = 0.0f;
#pragma unroll
        for (int r = 0; r < 16; r++) { float p = __builtin_amdgcn_exp2f(s0[r] - mnew); s0[r] = p; psum += p; }
#pragma unroll
        for (int r = 0; r < 16; r++) { float p = __builtin_amdgcn_exp2f(s1[r] - mnew); s1[r] = p; psum += p; }
        psum += __shfl_xor(psum, 32);
        ls = ls * alpha + psum;
        of0 = of0 * alpha;
        of1 = of1 * alpha;
      }
      // ---- P^T -> PV B-frags, fully in-register (T12) ----
      bf16x8 pf[4];
#pragma unroll
      for (int kt = 0; kt < 2; kt++) {
        f32x16& s = kt ? s1 : s0;
        unsigned x0 = cvtpk(s[0], s[1]),   x1 = cvtpk(s[2], s[3]);
        unsigned x2 = cvtpk(s[4], s[5]),   x3 = cvtpk(s[6], s[7]);
        unsigned y0 = cvtpk(s[8], s[9]),   y1 = cvtpk(s[10], s[11]);
        unsigned y2 = cvtpk(s[12], s[13]), y3 = cvtpk(s[14], s[15]);
        uint32x2 r02 = __builtin_amdgcn_permlane32_swap(x0, x2, false, false);
        uint32x2 r13 = __builtin_amdgcn_permlane32_swap(x1, x3, false, false);
        uint32x2 t02 = __builtin_amdgcn_permlane32_swap(y0, y2, false, false);
        uint32x2 t13 = __builtin_amdgcn_permlane32_swap(y1, y3, false, false);
        uint4 pa, pb2;
        pa.x = r02[0]; pa.y = r13[0]; pa.z = r02[1]; pa.w = r13[1];
        pb2.x = t02[0]; pb2.y = t13[0]; pb2.z = t02[1]; pb2.w = t13[1];
        pf[kt * 2]     = __builtin_bit_cast(bf16x8, pa);
        pf[kt * 2 + 1] = __builtin_bit_cast(bf16x8, pb2);
      }
      // ---- PV: O^T += V^T . P^T ----
      __builtin_amdgcn_s_setprio(1);
#pragma unroll
      for (int ks = 0; ks < 4; ks++) {
        bf16x8 v0 = *(const bf16x8*)(VBc + lq * 128 + ((ks * 32 + g * 16) ^ swz));
        bf16x8 v1 = *(const bf16x8*)(VBc + (32 + lq) * 128 + ((ks * 32 + g * 16) ^ swz));
        of0 = __builtin_amdgcn_mfma_f32_32x32x16_bf16(v0, pf[ks], of0, 0, 0, 0);
        of1 = __builtin_amdgcn_mfma_f32_32x32x16_bf16(v1, pf[ks], of1, 0, 0, 0);
      }
      __builtin_amdgcn_s_setprio(0);
    }
    if (t + 1 < nkv) {
      char* KBn = SMEM + ((t + 1) & 1) * 16384;
      char* VBn = KBn + 8192;
      *(uint4*)(KBn + sb0) = ka0;  *(uint4*)(KBn + sb1) = ka1;
      *(uint4*)(VBn + sb0) = va0;  *(uint4*)(VBn + sb1) = va1;
    }
    __syncthreads();
  }

  // ---- normalize + store via per-wave LDS transpose (buf0 region, wave-private) ----
  char* SB = SMEM + w * 4096;   // [32 q][64 d] bf16, swizzled rows
  float inv = 1.0f / ls;
#pragma unroll
  for (int j = 0; j < 8; j++) {
    int d0 = ((2 * j) & 3) + 8 * (j >> 1) + 4 * g;
    *(unsigned*)(SB + ((lq * 128 + d0 * 2) ^ swz)) = cvtpk(of0[2 * j] * inv, of0[2 * j + 1] * inv);
    *(unsigned*)(SB + ((lq * 128 + (32 + d0) * 2) ^ swz)) = cvtpk(of1[2 * j] * inv, of1[2 * j + 1] * inv);
  }
  {
    int r2 = l >> 1, half = l & 1;
    int X = (r2 & 7) << 4;
    unsigned short* orow = att + (size_t)(b * 2048 + wq + r2) * 1024 + h * 64 + half * 32;
#pragma unroll
    for (int i = 0; i < 4; i++) {
      uint4 o = *(const uint4*)(SB + ((r2 * 128 + half * 64 + i * 16) ^ X));
      *(uint4*)(orow + i * 8) = o;
    }
  }
}

extern "C" void kernel_launch(void* const* d_in, const int* in_sizes, int n_in,
                              void* d_out, int out_size, void* d_ws, size_t ws_size,
                              hipStream_t stream) {
  const float* x     = (const float*)d_in[0];
  const float* Wqkv  = (const float*)d_in[1];
  const float* Wproj = (const float*)d_in[2];
  float* out = (float*)d_out;

  char* ws = (char*)d_ws;
  size_t off = 0;
  auto alloc = [&](size_t bytes) { void* p = ws + off; off += (bytes + 255) & ~(size_t)255; return p; };
  unsigned short* xb   = (unsigned short*)alloc((size_t)4096 * 1024 * 2);
  unsigned short* wqt  = (unsigned short*)alloc((size_t)3072 * 1024 * 2);
  unsigned short* wpt  = (unsigned short*)alloc((size_t)1024 * 1024 * 2);
  unsigned short* qh   = (unsigned short*)alloc((size_t)32 * 2048 * 64 * 2);
  unsigned short* kh   = (unsigned short*)alloc((size_t)32 * 2048 * 64 * 2);
  unsigned short* vt   = (unsigned short*)alloc((size_t)32 * 64 * 2048 * 2);
  unsigned short* att  = (unsigned short*)alloc((size_t)4096 * 1024 * 2);
  float2* cstab = (float2*)alloc((size_t)2048 * 32 * 8);

  k_prep<<<8448, 256, 0, stream>>>(x, Wqkv, Wproj, xb, wqt, wpt, cstab);
  k_gemm_qkv<<<dim3(24, 32), 256, 0, stream>>>(xb, wqt, cstab, qh, kh, vt);
  k_attn<<<512, 256, 0, stream>>>(qh, kh, vt, att);
  k_gemm_proj<<<512, 256, 0, stream>>>(att, wpt, out);
}

// Round 10
// 107.124 us; speedup vs baseline: 1.0739x; 1.0739x over previous
//
#include <hip/hip_runtime.h>
#include <cstdint>
#include <cstddef>

typedef __attribute__((ext_vector_type(8))) short bf16x8;
typedef __attribute__((ext_vector_type(4))) float f32x4;

__device__ __forceinline__ unsigned short f2bf(float f) {
  unsigned int u = __builtin_bit_cast(unsigned int, f);
  u += 0x7FFFu + ((u >> 16) & 1u);
  return (unsigned short)(u >> 16);
}
__device__ __forceinline__ float bf2f(unsigned short h) {
  unsigned int u = ((unsigned int)h) << 16;
  return __builtin_bit_cast(float, u);
}

__device__ __forceinline__ void gl_lds16(const unsigned short* g, unsigned short* l) {
  __builtin_amdgcn_global_load_lds(
      (const __attribute__((address_space(1))) unsigned int*)(uintptr_t)g,
      (__attribute__((address_space(3))) unsigned int*)(unsigned int)(uintptr_t)l,
      16, 0, 0);
}

// ============ k_prep: convert(x) + wtrans(Wqkv) + wtrans(Wproj) + rope table ============
__global__ void k_prep(const float* __restrict__ x,
                       const float* __restrict__ Wqkv,
                       const float* __restrict__ Wproj,
                       unsigned short* __restrict__ xb,
                       unsigned short* __restrict__ wqt,
                       unsigned short* __restrict__ wpt,
                       float2* __restrict__ cstab) {
  __shared__ float tile[32][33];
  const int bid = blockIdx.x, tid = threadIdx.x;
  if (bid < 4096) {
    int i = bid * 256 + tid;
    float4 v = reinterpret_cast<const float4*>(x)[i];
    uint2 o;
    o.x = (unsigned int)f2bf(v.x) | ((unsigned int)f2bf(v.y) << 16);
    o.y = (unsigned int)f2bf(v.z) | ((unsigned int)f2bf(v.w) << 16);
    reinterpret_cast<uint2*>(xb)[i] = o;
  } else if (bid < 8192) {
    const float* in; unsigned short* out; int rows, cols, bx, by;
    if (bid < 7168) { in = Wqkv; out = wqt; rows = 1024; cols = 3072; bx = (bid - 4096) % 96; by = (bid - 4096) / 96; }
    else            { in = Wproj; out = wpt; rows = 1024; cols = 1024; bx = (bid - 7168) % 32; by = (bid - 7168) / 32; }
    int c0 = bx * 32, r0 = by * 32;
    int tx = tid & 31, ty = tid >> 5;
#pragma unroll
    for (int j = 0; j < 4; j++)
      tile[ty + j * 8][tx] = in[(size_t)(r0 + ty + j * 8) * cols + c0 + tx];
    __syncthreads();
#pragma unroll
    for (int j = 0; j < 4; j++)
      out[(size_t)(c0 + ty + j * 8) * rows + r0 + tx] = f2bf(tile[tx][ty + j * 8]);
  } else {
    int i = (bid - 8192) * 256 + tid;   // t*32 + j
    int t = i >> 5, j = i & 31;
    float invf = __powf(10000.0f, -(float)j / 32.0f);
    float ang = (float)t * invf;
    cstab[i] = make_float2(cosf(ang), sinf(ang));
  }
}

// ============ qkv GEMM with fused RoPE/head-split/V-transpose epilogue ============
__global__ void k_gemm_qkv(const unsigned short* __restrict__ A,
                           const unsigned short* __restrict__ Bt,
                           const float2* __restrict__ cstab,
                           unsigned short* __restrict__ qh,
                           unsigned short* __restrict__ kh,
                           unsigned short* __restrict__ vt) {
  const int K = 1024;
  __shared__ unsigned short Ta[128 * 32];
  __shared__ unsigned short Tb[128 * 32];
  const int tid = threadIdx.x;
  const int bid0 = blockIdx.y * 24 + blockIdx.x;
  const int bid = (bid0 & 7) * 96 + (bid0 >> 3);
  const int m0 = (bid / 24) * 128, n0 = (bid % 24) * 128;
  const int w = tid >> 6, l = tid & 63;
  const int lr = l & 15, lg = l >> 4;
  const int wm = (w >> 1) * 64, wn = (w & 1) * 64;
  const int ssr = w * 32 + (l >> 2);
  const int ssc = (l & 3) * 8;
  unsigned short* ta0 = &Ta[w * 1024];
  unsigned short* tb0 = &Tb[w * 1024];
  f32x4 acc[4][4] = {};
  for (int k0 = 0; k0 < K; k0 += 32) {
    __syncthreads();
    gl_lds16(&A[(size_t)(m0 + ssr) * K + k0 + ssc],       ta0);
    gl_lds16(&A[(size_t)(m0 + ssr + 16) * K + k0 + ssc],  ta0 + 512);
    gl_lds16(&Bt[(size_t)(n0 + ssr) * K + k0 + ssc],      tb0);
    gl_lds16(&Bt[(size_t)(n0 + ssr + 16) * K + k0 + ssc], tb0 + 512);
    __syncthreads();
    bf16x8 af[4], bfr[4];
#pragma unroll
    for (int i = 0; i < 4; i++)
      af[i] = *(const bf16x8*)&Ta[(wm + i * 16 + lr) * 32 + lg * 8];
#pragma unroll
    for (int j = 0; j < 4; j++)
      bfr[j] = *(const bf16x8*)&Tb[(wn + j * 16 + lr) * 32 + lg * 8];
#pragma unroll
    for (int i = 0; i < 4; i++)
#pragma unroll
      for (int j = 0; j < 4; j++)
        acc[i][j] = __builtin_amdgcn_mfma_f32_16x16x32_bf16(af[i], bfr[j], acc[i][j], 0, 0, 0);
  }
  const int part = n0 >> 10;                 // 0=q, 1=k, 2=v (block-uniform)
  const int hbase = (n0 & 1023) + wn;        // multiple of 64
  if (part < 2) {
    unsigned short* dst = part ? kh : qh;
    const float scale = part ? 1.0f : 0.180336880111120420f;
#pragma unroll
    for (int i = 0; i < 4; i++) {
#pragma unroll
      for (int r = 0; r < 4; r++) {
        int gm = m0 + wm + i * 16 + lg * 4 + r;
        int t = gm & 2047, b = gm >> 11;
        float2 cs0 = cstab[t * 32 + lr];
        float2 cs1 = cstab[t * 32 + 16 + lr];
#pragma unroll
        for (int j = 0; j < 4; j++) {
          float val = acc[i][j][r];
          float par = acc[i][j ^ 2][r];
          float2 cs = (j & 1) ? cs1 : cs0;
          float out = (j < 2) ? (val * cs.x - par * cs.y)
                              : (val * cs.x + par * cs.y);
          int h = (hbase + j * 16) >> 6;
          int d = j * 16 + lr;
          int bh = b * 16 + h;
          dst[((size_t)(bh * 2048 + t)) * 64 + d] = f2bf(out * scale);
        }
      }
    }
  } else {
#pragma unroll
    for (int i = 0; i < 4; i++) {
      int tb = m0 + wm + i * 16 + lg * 4;
      int t0 = tb & 2047, b = tb >> 11;
#pragma unroll
      for (int j = 0; j < 4; j++) {
        int h = (hbase + j * 16) >> 6;
        int d = j * 16 + lr;
        int bh = b * 16 + h;
        unsigned short pv[4];
#pragma unroll
        for (int r = 0; r < 4; r++) pv[r] = f2bf(acc[i][j][r]);
        *(uint2*)&vt[((size_t)(bh * 64 + d)) * 2048 + t0] = *(uint2*)pv;
      }
    }
  }
}

// ============ proj GEMM: out[4096][1024] f32 = att x wpt^T, 64x128 tiles ============
__global__ void k_gemm_proj(const unsigned short* __restrict__ A,
                            const unsigned short* __restrict__ Bt,
                            float* __restrict__ C) {
  const int K = 1024;
  __shared__ unsigned short Ta[64 * 32];
  __shared__ unsigned short Tb[128 * 32];
  const int tid = threadIdx.x;
  const int bid0 = blockIdx.x;
  const int bid = (bid0 & 7) * 64 + (bid0 >> 3);
  const int n0 = (bid & 7) * 128;
  const int m0 = (bid >> 3) * 64;
  const int w = tid >> 6, l = tid & 63;
  const int lr = l & 15, lg = l >> 4;
  const int wn = w * 32;
  const int sra = tid >> 2, sca = (tid & 3) * 8;
  f32x4 acc[4][2] = {};
  for (int k0 = 0; k0 < K; k0 += 32) {
    __syncthreads();
    gl_lds16(&A[(size_t)(m0 + sra) * K + k0 + sca],        &Ta[tid * 8]);
    gl_lds16(&Bt[(size_t)(n0 + sra) * K + k0 + sca],       &Tb[tid * 8]);
    gl_lds16(&Bt[(size_t)(n0 + 64 + sra) * K + k0 + sca],  &Tb[(tid + 256) * 8]);
    __syncthreads();
    bf16x8 af[4], bfr[2];
#pragma unroll
    for (int i = 0; i < 4; i++)
      af[i] = *(const bf16x8*)&Ta[(i * 16 + lr) * 32 + lg * 8];
#pragma unroll
    for (int j = 0; j < 2; j++)
      bfr[j] = *(const bf16x8*)&Tb[(wn + j * 16 + lr) * 32 + lg * 8];
#pragma unroll
    for (int i = 0; i < 4; i++)
#pragma unroll
      for (int j = 0; j < 2; j++)
        acc[i][j] = __builtin_amdgcn_mfma_f32_16x16x32_bf16(af[i], bfr[j], acc[i][j], 0, 0, 0);
  }
#pragma unroll
  for (int i = 0; i < 4; i++)
#pragma unroll
    for (int j = 0; j < 2; j++)
#pragma unroll
      for (int r = 0; r < 4; r++)
        C[(size_t)(m0 + i * 16 + lg * 4 + r) * 1024 + n0 + wn + j * 16 + lr] = acc[i][j][r];
}

// ---------------- causal flash attention: R3 core + single-barrier dbuf + defer-max ----
// 512 blocks x 4 waves (2/CU). Block: sequential pair {qt0, 31-qt0} of 64-row tiles,
// exactly 33 uniform KV-64 steps. K/V double-buffered: issue(t+1) global->reg at step
// top (latency under compute), write regs->buf[(t+1)&1] at bottom, ONE barrier/step.
// Swapped QK^T (16x16), T13 defer-max, T5 setprio, XOR-swizzled LDS, XCD head-major.
__global__ __launch_bounds__(256, 2) void k_attn(const unsigned short* __restrict__ qh,
                       const unsigned short* __restrict__ kh,
                       const unsigned short* __restrict__ vt,
                       unsigned short* __restrict__ att) {
  __shared__ char SMEM[40960];   // K0 8K | K1 8K | V0 8K | V1 8K | P 4x2K
  const int bid = blockIdx.x;
  const int bh  = ((bid & 7) << 2) | ((bid >> 3) >> 4);   // head-major per XCD
  const int qt0 = (bid >> 3) & 15;
  const int qt1 = 31 - qt0;
  const int b = bh >> 4, h = bh & 15;
  const int tid = threadIdx.x;
  const int w = tid >> 6, l = tid & 63;
  const int lr = l & 15, lg = l >> 4;
  const unsigned short* qbase = qh + (size_t)bh * 2048 * 64;
  const unsigned short* kbase = kh + (size_t)bh * 2048 * 64;
  const unsigned short* vbase = vt + (size_t)bh * 64 * 2048;
  char* PB = SMEM + 32768 + w * 2048;
  const int swz = (lr & 7) << 4;
  const int sr = tid >> 2, sc = (tid & 3) * 16;
  const int sb0 = (sr * 128 + sc * 2) ^ ((sr & 7) << 4);
  const int sb1 = (sr * 128 + sc * 2 + 16) ^ ((sr & 7) << 4);

  const int q00 = qt0 * 64, q01 = qt1 * 64;
  const int qrow0 = q00 + w * 16 + lr;
  const int qrow1 = q01 + w * 16 + lr;
  bf16x8 qa0 = *(const bf16x8*)&qbase[(size_t)qrow0 * 64 + lg * 8];
  bf16x8 qb0 = *(const bf16x8*)&qbase[(size_t)qrow0 * 64 + 32 + lg * 8];
  bf16x8 qa1 = *(const bf16x8*)&qbase[(size_t)qrow1 * 64 + lg * 8];
  bf16x8 qb1 = *(const bf16x8*)&qbase[(size_t)qrow1 * 64 + 32 + lg * 8];

  float mr0 = -3.0e38f, ls0 = 0.0f;
  float mr1 = -3.0e38f, ls1 = 0.0f;
  f32x4 of0[4] = {}, of1[4] = {};
  uint4 ka0, ka1, va0, va1;   // in-flight K/V tile (T14)

  auto issue = [&](int kv0) {
    const unsigned short* ksrc = &kbase[(size_t)(kv0 + sr) * 64 + sc];
    const unsigned short* vsrc = &vbase[(size_t)sr * 2048 + kv0 + sc];
    ka0 = *(const uint4*)ksrc; ka1 = *(const uint4*)(ksrc + 8);
    va0 = *(const uint4*)vsrc; va1 = *(const uint4*)(vsrc + 8);
  };

  auto step = [&](f32x4 (&of)[4], float& mr, float& ls, bf16x8 qa, bf16x8 qb,
                  int qrow, int kv0, bool diag, char* KB, char* VB) {
    f32x4 s[4] = {};
    __builtin_amdgcn_s_setprio(1);
#pragma unroll
    for (int kq = 0; kq < 4; kq++) {
      bf16x8 kf0 = *(const bf16x8*)(KB + (((kq * 16 + lr) * 128 + lg * 16) ^ swz));
      bf16x8 kf1 = *(const bf16x8*)(KB + (((kq * 16 + lr) * 128 + 64 + lg * 16) ^ swz));
      s[kq] = __builtin_amdgcn_mfma_f32_16x16x32_bf16(kf0, qa, s[kq], 0, 0, 0);
      s[kq] = __builtin_amdgcn_mfma_f32_16x16x32_bf16(kf1, qb, s[kq], 0, 0, 0);
    }
    __builtin_amdgcn_s_setprio(0);
    if (diag) {
#pragma unroll
      for (int kq = 0; kq < 4; kq++)
#pragma unroll
        for (int r = 0; r < 4; r++)
          if (kv0 + kq * 16 + lg * 4 + r > qrow) s[kq][r] = -3.0e38f;
    }
    float pm = s[0][0];
#pragma unroll
    for (int kq = 0; kq < 4; kq++)
#pragma unroll
      for (int r = 0; r < 4; r++) pm = fmaxf(pm, s[kq][r]);
    pm = fmaxf(pm, __shfl_xor(pm, 16));
    pm = fmaxf(pm, __shfl_xor(pm, 32));
    float psum = 0.0f;
    if (__all(pm <= mr)) {            // T13: no rescale pass
#pragma unroll
      for (int kq = 0; kq < 4; kq++)
#pragma unroll
        for (int r = 0; r < 4; r++) {
          float p = __builtin_amdgcn_exp2f(s[kq][r] - mr);
          s[kq][r] = p;
          psum += p;
        }
      psum += __shfl_xor(psum, 16);
      psum += __shfl_xor(psum, 32);
      ls += psum;
    } else {
      float mnew = fmaxf(mr, pm);
      float alpha = __builtin_amdgcn_exp2f(mr - mnew);
      mr = mnew;
#pragma unroll
      for (int kq = 0; kq < 4; kq++)
#pragma unroll
        for (int r = 0; r < 4; r++) {
          float p = __builtin_amdgcn_exp2f(s[kq][r] - mnew);
          s[kq][r] = p;
          psum += p;
        }
      psum += __shfl_xor(psum, 16);
      psum += __shfl_xor(psum, 32);
      ls = ls * alpha + psum;
#pragma unroll
      for (int n = 0; n < 4; n++) {
        of[n][0] *= alpha; of[n][1] *= alpha; of[n][2] *= alpha; of[n][3] *= alpha;
      }
    }
    // P -> per-wave LDS [q][k] (wave-synchronous)
#pragma unroll
    for (int kq = 0; kq < 4; kq++) {
      uint2 pk;
      asm("v_cvt_pk_bf16_f32 %0, %1, %2" : "=v"(pk.x) : "v"(s[kq][0]), "v"(s[kq][1]));
      asm("v_cvt_pk_bf16_f32 %0, %1, %2" : "=v"(pk.y) : "v"(s[kq][2]), "v"(s[kq][3]));
      *(uint2*)(PB + ((lr * 128 + (kq * 16 + lg * 4) * 2) ^ swz)) = pk;
    }
    bf16x8 pb0 = *(const bf16x8*)(PB + ((lr * 128 + lg * 16) ^ swz));
    bf16x8 pb1 = *(const bf16x8*)(PB + ((lr * 128 + 64 + lg * 16) ^ swz));
    __builtin_amdgcn_s_setprio(1);
#pragma unroll
    for (int n = 0; n < 4; n++) {
      bf16x8 vf0 = *(const bf16x8*)(VB + (((n * 16 + lr) * 128 + lg * 16) ^ swz));
      bf16x8 vf1 = *(const bf16x8*)(VB + (((n * 16 + lr) * 128 + 64 + lg * 16) ^ swz));
      of[n] = __builtin_amdgcn_mfma_f32_16x16x32_bf16(vf0, pb0, of[n], 0, 0, 0);
      of[n] = __builtin_amdgcn_mfma_f32_16x16x32_bf16(vf1, pb1, of[n], 0, 0, 0);
    }
    __builtin_amdgcn_s_setprio(0);
  };

  const int nkv0 = qt0 + 1;
  issue(0);
  {
    char* KB0 = SMEM;
    char* VB0 = SMEM + 16384;
    *(uint4*)(KB0 + sb0) = ka0;  *(uint4*)(KB0 + sb1) = ka1;
    *(uint4*)(VB0 + sb0) = va0;  *(uint4*)(VB0 + sb1) = va1;
  }
  __syncthreads();

  for (int s2 = 0; s2 < 33; s2++) {
    if (s2 < 32) {                        // T14: next tile global->reg, hidden under compute
      int ns = s2 + 1;
      issue(((ns < nkv0) ? ns : ns - nkv0) * 64);
    }
    char* KB = SMEM + (s2 & 1) * 8192;
    char* VB = SMEM + 16384 + (s2 & 1) * 8192;
    if (s2 < nkv0) step(of0, mr0, ls0, qa0, qb0, qrow0, s2 * 64, s2 == qt0, KB, VB);
    else           step(of1, mr1, ls1, qa1, qb1, qrow1, (s2 - nkv0) * 64, s2 == 32, KB, VB);
    if (s2 < 32) {                        // publish tile s2+1 into the other buffer
      char* KBn = SMEM + ((s2 + 1) & 1) * 8192;
      char* VBn = SMEM + 16384 + ((s2 + 1) & 1) * 8192;
      *(uint4*)(KBn + sb0) = ka0;  *(uint4*)(KBn + sb1) = ka1;
      *(uint4*)(VBn + sb0) = va0;  *(uint4*)(VBn + sb1) = va1;
    }
    __syncthreads();
  }

  auto store_half = [&](f32x4 (&of)[4], float ls, int q0) {
    float inv = 1.0f / ls;
#pragma unroll
    for (int n = 0; n < 4; n++) {
      uint2 pk;
      float o0 = of[n][0] * inv, o1 = of[n][1] * inv, o2 = of[n][2] * inv, o3 = of[n][3] * inv;
      asm("v_cvt_pk_bf16_f32 %0, %1, %2" : "=v"(pk.x) : "v"(o0), "v"(o1));
      asm("v_cvt_pk_bf16_f32 %0, %1, %2" : "=v"(pk.y) : "v"(o2), "v"(o3));
      *(uint2*)(PB + ((lr * 128 + (n * 16 + lg * 4) * 2) ^ swz)) = pk;
    }
    int r2 = l >> 2, c2 = (l & 3) * 16;
    int bo0 = (r2 * 128 + c2 * 2) ^ ((r2 & 7) << 4);
    int bo1 = (r2 * 128 + c2 * 2 + 16) ^ ((r2 & 7) << 4);
    uint4 o0 = *(const uint4*)(PB + bo0);
    uint4 o1 = *(const uint4*)(PB + bo1);
    unsigned short* orow = att + (size_t)(b * 2048 + q0 + w * 16 + r2) * 1024 + h * 64 + c2;
    *(uint4*)orow = o0;
    *(uint4*)(orow + 8) = o1;
  };
  store_half(of0, ls0, q00);
  store_half(of1, ls1, q01);
}

extern "C" void kernel_launch(void* const* d_in, const int* in_sizes, int n_in,
                              void* d_out, int out_size, void* d_ws, size_t ws_size,
                              hipStream_t stream) {
  const float* x     = (const float*)d_in[0];
  const float* Wqkv  = (const float*)d_in[1];
  const float* Wproj = (const float*)d_in[2];
  float* out = (float*)d_out;

  char* ws = (char*)d_ws;
  size_t off = 0;
  auto alloc = [&](size_t bytes) { void* p = ws + off; off += (bytes + 255) & ~(size_t)255; return p; };
  unsigned short* xb   = (unsigned short*)alloc((size_t)4096 * 1024 * 2);
  unsigned short* wqt  = (unsigned short*)alloc((size_t)3072 * 1024 * 2);
  unsigned short* wpt  = (unsigned short*)alloc((size_t)1024 * 1024 * 2);
  unsigned short* qh   = (unsigned short*)alloc((size_t)32 * 2048 * 64 * 2);
  unsigned short* kh   = (unsigned short*)alloc((size_t)32 * 2048 * 64 * 2);
  unsigned short* vt   = (unsigned short*)alloc((size_t)32 * 64 * 2048 * 2);
  unsigned short* att  = (unsigned short*)alloc((size_t)4096 * 1024 * 2);
  float2* cstab = (float2*)alloc((size_t)2048 * 32 * 8);

  k_prep<<<8448, 256, 0, stream>>>(x, Wqkv, Wproj, xb, wqt, wpt, cstab);
  k_gemm_qkv<<<dim3(24, 32), 256, 0, stream>>>(xb, wqt, cstab, qh, kh, vt);
  k_attn<<<512, 256, 0, stream>>>(qh, kh, vt, att);
  k_gemm_proj<<<512, 256, 0, stream>>>(att, wpt, out);
}

// Round 11
// 105.339 us; speedup vs baseline: 1.0921x; 1.0169x over previous
//
#include <hip/hip_runtime.h>
#include <cstdint>
#include <cstddef>

typedef __attribute__((ext_vector_type(8))) short bf16x8;
typedef __attribute__((ext_vector_type(4))) float f32x4;

__device__ __forceinline__ unsigned short f2bf(float f) {
  unsigned int u = __builtin_bit_cast(unsigned int, f);
  u += 0x7FFFu + ((u >> 16) & 1u);
  return (unsigned short)(u >> 16);
}
__device__ __forceinline__ float bf2f(unsigned short h) {
  unsigned int u = ((unsigned int)h) << 16;
  return __builtin_bit_cast(float, u);
}

__device__ __forceinline__ void gl_lds16(const unsigned short* g, unsigned short* l) {
  __builtin_amdgcn_global_load_lds(
      (const __attribute__((address_space(1))) unsigned int*)(uintptr_t)g,
      (__attribute__((address_space(3))) unsigned int*)(unsigned int)(uintptr_t)l,
      16, 0, 0);
}

// ============ k_prep: convert(x) + wtrans(Wqkv) + wtrans(Wproj) + rope table ============
__global__ void k_prep(const float* __restrict__ x,
                       const float* __restrict__ Wqkv,
                       const float* __restrict__ Wproj,
                       unsigned short* __restrict__ xb,
                       unsigned short* __restrict__ wqt,
                       unsigned short* __restrict__ wpt,
                       float2* __restrict__ cstab) {
  __shared__ float tile[32][33];
  const int bid = blockIdx.x, tid = threadIdx.x;
  if (bid < 4096) {
    int i = bid * 256 + tid;
    float4 v = reinterpret_cast<const float4*>(x)[i];
    uint2 o;
    o.x = (unsigned int)f2bf(v.x) | ((unsigned int)f2bf(v.y) << 16);
    o.y = (unsigned int)f2bf(v.z) | ((unsigned int)f2bf(v.w) << 16);
    reinterpret_cast<uint2*>(xb)[i] = o;
  } else if (bid < 8192) {
    const float* in; unsigned short* out; int rows, cols, bx, by;
    if (bid < 7168) { in = Wqkv; out = wqt; rows = 1024; cols = 3072; bx = (bid - 4096) % 96; by = (bid - 4096) / 96; }
    else            { in = Wproj; out = wpt; rows = 1024; cols = 1024; bx = (bid - 7168) % 32; by = (bid - 7168) / 32; }
    int c0 = bx * 32, r0 = by * 32;
    int tx = tid & 31, ty = tid >> 5;
#pragma unroll
    for (int j = 0; j < 4; j++)
      tile[ty + j * 8][tx] = in[(size_t)(r0 + ty + j * 8) * cols + c0 + tx];
    __syncthreads();
#pragma unroll
    for (int j = 0; j < 4; j++)
      out[(size_t)(c0 + ty + j * 8) * rows + r0 + tx] = f2bf(tile[tx][ty + j * 8]);
  } else {
    int i = (bid - 8192) * 256 + tid;   // t*32 + j
    int t = i >> 5, j = i & 31;
    float invf = __powf(10000.0f, -(float)j / 32.0f);
    float ang = (float)t * invf;
    cstab[i] = make_float2(cosf(ang), sinf(ang));
  }
}

// ============ qkv GEMM with fused RoPE/head-split/V-transpose epilogue ============
__global__ void k_gemm_qkv(const unsigned short* __restrict__ A,
                           const unsigned short* __restrict__ Bt,
                           const float2* __restrict__ cstab,
                           unsigned short* __restrict__ qh,
                           unsigned short* __restrict__ kh,
                           unsigned short* __restrict__ vt) {
  const int K = 1024;
  __shared__ unsigned short Ta[128 * 32];
  __shared__ unsigned short Tb[128 * 32];
  const int tid = threadIdx.x;
  const int bid0 = blockIdx.y * 24 + blockIdx.x;
  const int bid = (bid0 & 7) * 96 + (bid0 >> 3);
  const int m0 = (bid / 24) * 128, n0 = (bid % 24) * 128;
  const int w = tid >> 6, l = tid & 63;
  const int lr = l & 15, lg = l >> 4;
  const int wm = (w >> 1) * 64, wn = (w & 1) * 64;
  const int ssr = w * 32 + (l >> 2);
  const int ssc = (l & 3) * 8;
  unsigned short* ta0 = &Ta[w * 1024];
  unsigned short* tb0 = &Tb[w * 1024];
  f32x4 acc[4][4] = {};
  for (int k0 = 0; k0 < K; k0 += 32) {
    __syncthreads();
    gl_lds16(&A[(size_t)(m0 + ssr) * K + k0 + ssc],       ta0);
    gl_lds16(&A[(size_t)(m0 + ssr + 16) * K + k0 + ssc],  ta0 + 512);
    gl_lds16(&Bt[(size_t)(n0 + ssr) * K + k0 + ssc],      tb0);
    gl_lds16(&Bt[(size_t)(n0 + ssr + 16) * K + k0 + ssc], tb0 + 512);
    __syncthreads();
    bf16x8 af[4], bfr[4];
#pragma unroll
    for (int i = 0; i < 4; i++)
      af[i] = *(const bf16x8*)&Ta[(wm + i * 16 + lr) * 32 + lg * 8];
#pragma unroll
    for (int j = 0; j < 4; j++)
      bfr[j] = *(const bf16x8*)&Tb[(wn + j * 16 + lr) * 32 + lg * 8];
#pragma unroll
    for (int i = 0; i < 4; i++)
#pragma unroll
      for (int j = 0; j < 4; j++)
        acc[i][j] = __builtin_amdgcn_mfma_f32_16x16x32_bf16(af[i], bfr[j], acc[i][j], 0, 0, 0);
  }
  const int part = n0 >> 10;                 // 0=q, 1=k, 2=v (block-uniform)
  const int hbase = (n0 & 1023) + wn;        // multiple of 64
  if (part < 2) {
    unsigned short* dst = part ? kh : qh;
    const float scale = part ? 1.0f : 0.180336880111120420f;
#pragma unroll
    for (int i = 0; i < 4; i++) {
#pragma unroll
      for (int r = 0; r < 4; r++) {
        int gm = m0 + wm + i * 16 + lg * 4 + r;
        int t = gm & 2047, b = gm >> 11;
        float2 cs0 = cstab[t * 32 + lr];
        float2 cs1 = cstab[t * 32 + 16 + lr];
#pragma unroll
        for (int j = 0; j < 4; j++) {
          float val = acc[i][j][r];
          float par = acc[i][j ^ 2][r];
          float2 cs = (j & 1) ? cs1 : cs0;
          float out = (j < 2) ? (val * cs.x - par * cs.y)
                              : (val * cs.x + par * cs.y);
          int h = (hbase + j * 16) >> 6;
          int d = j * 16 + lr;
          int bh = b * 16 + h;
          dst[((size_t)(bh * 2048 + t)) * 64 + d] = f2bf(out * scale);
        }
      }
    }
  } else {
#pragma unroll
    for (int i = 0; i < 4; i++) {
      int tb = m0 + wm + i * 16 + lg * 4;
      int t0 = tb & 2047, b = tb >> 11;
#pragma unroll
      for (int j = 0; j < 4; j++) {
        int h = (hbase + j * 16) >> 6;
        int d = j * 16 + lr;
        int bh = b * 16 + h;
        unsigned short pv[4];
#pragma unroll
        for (int r = 0; r < 4; r++) pv[r] = f2bf(acc[i][j][r]);
        *(uint2*)&vt[((size_t)(bh * 64 + d)) * 2048 + t0] = *(uint2*)pv;
      }
    }
  }
}

// ============ proj GEMM: out[4096][1024] f32 = att x wpt^T, 64x128 tiles ============
__global__ void k_gemm_proj(const unsigned short* __restrict__ A,
                            const unsigned short* __restrict__ Bt,
                            float* __restrict__ C) {
  const int K = 1024;
  __shared__ unsigned short Ta[64 * 32];
  __shared__ unsigned short Tb[128 * 32];
  const int tid = threadIdx.x;
  const int bid0 = blockIdx.x;
  const int bid = (bid0 & 7) * 64 + (bid0 >> 3);
  const int n0 = (bid & 7) * 128;
  const int m0 = (bid >> 3) * 64;
  const int w = tid >> 6, l = tid & 63;
  const int lr = l & 15, lg = l >> 4;
  const int wn = w * 32;
  const int sra = tid >> 2, sca = (tid & 3) * 8;
  f32x4 acc[4][2] = {};
  for (int k0 = 0; k0 < K; k0 += 32) {
    __syncthreads();
    gl_lds16(&A[(size_t)(m0 + sra) * K + k0 + sca],        &Ta[tid * 8]);
    gl_lds16(&Bt[(size_t)(n0 + sra) * K + k0 + sca],       &Tb[tid * 8]);
    gl_lds16(&Bt[(size_t)(n0 + 64 + sra) * K + k0 + sca],  &Tb[(tid + 256) * 8]);
    __syncthreads();
    bf16x8 af[4], bfr[2];
#pragma unroll
    for (int i = 0; i < 4; i++)
      af[i] = *(const bf16x8*)&Ta[(i * 16 + lr) * 32 + lg * 8];
#pragma unroll
    for (int j = 0; j < 2; j++)
      bfr[j] = *(const bf16x8*)&Tb[(wn + j * 16 + lr) * 32 + lg * 8];
#pragma unroll
    for (int i = 0; i < 4; i++)
#pragma unroll
      for (int j = 0; j < 2; j++)
        acc[i][j] = __builtin_amdgcn_mfma_f32_16x16x32_bf16(af[i], bfr[j], acc[i][j], 0, 0, 0);
  }
#pragma unroll
  for (int i = 0; i < 4; i++)
#pragma unroll
    for (int j = 0; j < 2; j++)
#pragma unroll
      for (int r = 0; r < 4; r++)
        C[(size_t)(m0 + i * 16 + lg * 4 + r) * 1024 + n0 + wn + j * 16 + lr] = acc[i][j][r];
}

// ---------------- causal flash attention: R3 step, 1 tile/block, 4 blocks/CU ----------
// 1024 blocks, one 64-row q-tile each, __launch_bounds__(256,4), LDS 24KB.
// Dispatch model (validated by R4 magnitude analysis): xcd = bid&7; within an XCD,
// CU = (bid>>3) % 32. Per XCD: u = bid>>3 = hl*32 + v, head hl in [0,4), v = CU.
// Tile permutation per head makes every CU's 4 resident blocks sum to 66 steps:
//   qt(0,v)=v; qt(1,v)=31-v; qt(2,v)=(v+16)%32; qt(3,v)=(47-v)%32  (bijective per hl).
// Step body = R3 verbatim: swapped QK^T 16x16, T14 reg-prefetch, 2 barriers,
// XOR-swizzled LDS, setprio, P round-trip via per-wave LDS.
__global__ __launch_bounds__(256, 4) void k_attn(const unsigned short* __restrict__ qh,
                       const unsigned short* __restrict__ kh,
                       const unsigned short* __restrict__ vt,
                       unsigned short* __restrict__ att) {
  __shared__ unsigned short Kl[64 * 64];   // [k][d]
  __shared__ unsigned short Vl[64 * 64];   // [d][k]  (V^T)
  __shared__ unsigned short Pl[4][16 * 64];// per-wave [q][k]
  const int bid = blockIdx.x;
  const int xcd = bid & 7, u = bid >> 3;
  const int hl = u >> 5, v = u & 31;
  int qt;
  if      (hl == 0) qt = v;
  else if (hl == 1) qt = 31 - v;
  else if (hl == 2) qt = (v + 16) & 31;
  else              qt = (47 - v) & 31;
  const int bh = xcd * 4 + hl;
  const int b = bh >> 4, h = bh & 15;
  const int tid = threadIdx.x;
  const int w = tid >> 6, l = tid & 63;
  const int lr = l & 15, lg = l >> 4;
  const unsigned short* qbase = qh + (size_t)bh * 2048 * 64;
  const unsigned short* kbase = kh + (size_t)bh * 2048 * 64;
  const unsigned short* vbase = vt + (size_t)bh * 64 * 2048;
  char* KB = (char*)Kl;
  char* VB = (char*)Vl;
  char* PB = (char*)&Pl[w][0];
  const int swz = (lr & 7) << 4;
  const int sr = tid >> 2, sc = (tid & 3) * 16;
  const int sb0 = (sr * 128 + sc * 2) ^ ((sr & 7) << 4);
  const int sb1 = (sr * 128 + sc * 2 + 16) ^ ((sr & 7) << 4);

  const int q0 = qt * 64;
  const int qrow = q0 + w * 16 + lr;
  bf16x8 qa = *(const bf16x8*)&qbase[(size_t)qrow * 64 + lg * 8];
  bf16x8 qb = *(const bf16x8*)&qbase[(size_t)qrow * 64 + 32 + lg * 8];

  float mr = -3.0e38f, ls = 0.0f;
  f32x4 of[4] = {};
  uint4 ka0, ka1, va0, va1;   // in-flight K/V tile (T14)

  auto issue = [&](int kv0) {
    const unsigned short* ksrc = &kbase[(size_t)(kv0 + sr) * 64 + sc];
    const unsigned short* vsrc = &vbase[(size_t)sr * 2048 + kv0 + sc];
    ka0 = *(const uint4*)ksrc; ka1 = *(const uint4*)(ksrc + 8);
    va0 = *(const uint4*)vsrc; va1 = *(const uint4*)(vsrc + 8);
  };

  issue(0);
  for (int kb = 0; kb <= qt; kb++) {
    const int kv0 = kb * 64;
    __syncthreads();
    // stage in-flight regs -> LDS (compiler inserts the vmcnt wait here)
    *(uint4*)(KB + sb0) = ka0;  *(uint4*)(KB + sb1) = ka1;
    *(uint4*)(VB + sb0) = va0;  *(uint4*)(VB + sb1) = va1;
    __syncthreads();
    if (kb < qt) issue((kb + 1) * 64);   // T14: next tile in flight during compute

    f32x4 s[4] = {};
    __builtin_amdgcn_s_setprio(1);
#pragma unroll
    for (int kq = 0; kq < 4; kq++) {
      bf16x8 kf0 = *(const bf16x8*)(KB + (((kq * 16 + lr) * 128 + lg * 16) ^ swz));
      bf16x8 kf1 = *(const bf16x8*)(KB + (((kq * 16 + lr) * 128 + 64 + lg * 16) ^ swz));
      s[kq] = __builtin_amdgcn_mfma_f32_16x16x32_bf16(kf0, qa, s[kq], 0, 0, 0);
      s[kq] = __builtin_amdgcn_mfma_f32_16x16x32_bf16(kf1, qb, s[kq], 0, 0, 0);
    }
    __builtin_amdgcn_s_setprio(0);
    if (kb == qt) {  // diagonal block: causal mask
#pragma unroll
      for (int kq = 0; kq < 4; kq++)
#pragma unroll
        for (int r = 0; r < 4; r++)
          if (kv0 + kq * 16 + lg * 4 + r > qrow) s[kq][r] = -3.0e38f;
    }
    float pm = s[0][0];
#pragma unroll
    for (int kq = 0; kq < 4; kq++)
#pragma unroll
      for (int r = 0; r < 4; r++) pm = fmaxf(pm, s[kq][r]);
    pm = fmaxf(pm, __shfl_xor(pm, 16));
    pm = fmaxf(pm, __shfl_xor(pm, 32));
    float mnew = fmaxf(mr, pm);
    float alpha = __builtin_amdgcn_exp2f(mr - mnew);
    mr = mnew;
    float psum = 0.0f;
#pragma unroll
    for (int kq = 0; kq < 4; kq++)
#pragma unroll
      for (int r = 0; r < 4; r++) {
        float p = __builtin_amdgcn_exp2f(s[kq][r] - mnew);
        s[kq][r] = p;
        psum += p;
      }
    psum += __shfl_xor(psum, 16);
    psum += __shfl_xor(psum, 32);
    ls = ls * alpha + psum;
#pragma unroll
    for (int n = 0; n < 4; n++) {
      of[n][0] *= alpha; of[n][1] *= alpha; of[n][2] *= alpha; of[n][3] *= alpha;
    }
    // P -> per-wave LDS [q][k] (wave-synchronous)
#pragma unroll
    for (int kq = 0; kq < 4; kq++) {
      uint2 pk;
      asm("v_cvt_pk_bf16_f32 %0, %1, %2" : "=v"(pk.x) : "v"(s[kq][0]), "v"(s[kq][1]));
      asm("v_cvt_pk_bf16_f32 %0, %1, %2" : "=v"(pk.y) : "v"(s[kq][2]), "v"(s[kq][3]));
      *(uint2*)(PB + ((lr * 128 + (kq * 16 + lg * 4) * 2) ^ swz)) = pk;
    }
    bf16x8 pb0 = *(const bf16x8*)(PB + ((lr * 128 + lg * 16) ^ swz));
    bf16x8 pb1 = *(const bf16x8*)(PB + ((lr * 128 + 64 + lg * 16) ^ swz));
    __builtin_amdgcn_s_setprio(1);
#pragma unroll
    for (int n = 0; n < 4; n++) {
      bf16x8 vf0 = *(const bf16x8*)(VB + (((n * 16 + lr) * 128 + lg * 16) ^ swz));
      bf16x8 vf1 = *(const bf16x8*)(VB + (((n * 16 + lr) * 128 + 64 + lg * 16) ^ swz));
      of[n] = __builtin_amdgcn_mfma_f32_16x16x32_bf16(vf0, pb0, of[n], 0, 0, 0);
      of[n] = __builtin_amdgcn_mfma_f32_16x16x32_bf16(vf1, pb1, of[n], 0, 0, 0);
    }
    __builtin_amdgcn_s_setprio(0);
  }

  // normalize + store via per-wave LDS transpose (coalesced 128B rows)
  float inv = 1.0f / ls;
#pragma unroll
  for (int n = 0; n < 4; n++) {
    uint2 pk;
    float o0 = of[n][0] * inv, o1 = of[n][1] * inv, o2 = of[n][2] * inv, o3 = of[n][3] * inv;
    asm("v_cvt_pk_bf16_f32 %0, %1, %2" : "=v"(pk.x) : "v"(o0), "v"(o1));
    asm("v_cvt_pk_bf16_f32 %0, %1, %2" : "=v"(pk.y) : "v"(o2), "v"(o3));
    *(uint2*)(PB + ((lr * 128 + (n * 16 + lg * 4) * 2) ^ swz)) = pk;
  }
  {
    int r2 = l >> 2, c2 = (l & 3) * 16;
    int bo0 = (r2 * 128 + c2 * 2) ^ ((r2 & 7) << 4);
    int bo1 = (r2 * 128 + c2 * 2 + 16) ^ ((r2 & 7) << 4);
    uint4 o0 = *(const uint4*)(PB + bo0);
    uint4 o1 = *(const uint4*)(PB + bo1);
    unsigned short* orow = att + (size_t)(b * 2048 + q0 + w * 16 + r2) * 1024 + h * 64 + c2;
    *(uint4*)orow = o0;
    *(uint4*)(orow + 8) = o1;
  }
}

extern "C" void kernel_launch(void* const* d_in, const int* in_sizes, int n_in,
                              void* d_out, int out_size, void* d_ws, size_t ws_size,
                              hipStream_t stream) {
  const float* x     = (const float*)d_in[0];
  const float* Wqkv  = (const float*)d_in[1];
  const float* Wproj = (const float*)d_in[2];
  float* out = (float*)d_out;

  char* ws = (char*)d_ws;
  size_t off = 0;
  auto alloc = [&](size_t bytes) { void* p = ws + off; off += (bytes + 255) & ~(size_t)255; return p; };
  unsigned short* xb   = (unsigned short*)alloc((size_t)4096 * 1024 * 2);
  unsigned short* wqt  = (unsigned short*)alloc((size_t)3072 * 1024 * 2);
  unsigned short* wpt  = (unsigned short*)alloc((size_t)1024 * 1024 * 2);
  unsigned short* qh   = (unsigned short*)alloc((size_t)32 * 2048 * 64 * 2);
  unsigned short* kh   = (unsigned short*)alloc((size_t)32 * 2048 * 64 * 2);
  unsigned short* vt   = (unsigned short*)alloc((size_t)32 * 64 * 2048 * 2);
  unsigned short* att  = (unsigned short*)alloc((size_t)4096 * 1024 * 2);
  float2* cstab = (float2*)alloc((size_t)2048 * 32 * 8);

  k_prep<<<8448, 256, 0, stream>>>(x, Wqkv, Wproj, xb, wqt, wpt, cstab);
  k_gemm_qkv<<<dim3(24, 32), 256, 0, stream>>>(xb, wqt, cstab, qh, kh, vt);
  k_attn<<<1024, 256, 0, stream>>>(qh, kh, vt, att);
  k_gemm_proj<<<512, 256, 0, stream>>>(att, wpt, out);
}